// Round 1
// baseline (641.341 us; speedup 1.0000x reference)
//
#include <hip/hip_runtime.h>
#include <hip/hip_bf16.h>

#define N_NODES 1000000
#define D_FEAT 128
#define BATCH 100000
#define NUM_SAMPLE 10

// 32 threads per output row; each thread owns one float4 (4 feats).
// Row = 128 floats = 32 float4 = 512 B -> a half-wave reads one full row
// coalesced; two rows per wave64.
__global__ __launch_bounds__(256) void mean_agg_kernel(
    const float4* __restrict__ feat,   // [N_NODES * 32] float4
    const int* __restrict__ idx,       // [BATCH * NUM_SAMPLE]
    float4* __restrict__ out)          // [BATCH * 32] float4
{
    const int gid = blockIdx.x * blockDim.x + threadIdx.x;
    const int row = gid >> 5;        // output row
    const int col = gid & 31;        // float4 column within row
    if (row >= BATCH) return;

    const int* ip = idx + row * NUM_SAMPLE;

    float4 acc = make_float4(0.f, 0.f, 0.f, 0.f);
#pragma unroll
    for (int s = 0; s < NUM_SAMPLE; ++s) {
        const long long n = ip[s];
        const float4 v = feat[n * 32 + col];
        acc.x += v.x;
        acc.y += v.y;
        acc.z += v.z;
        acc.w += v.w;
    }
    const float inv = 1.0f / (float)NUM_SAMPLE;
    acc.x *= inv; acc.y *= inv; acc.z *= inv; acc.w *= inv;
    out[row * 32 + col] = acc;
}

extern "C" void kernel_launch(void* const* d_in, const int* in_sizes, int n_in,
                              void* d_out, int out_size, void* d_ws, size_t ws_size,
                              hipStream_t stream) {
    const float4* feat = (const float4*)d_in[0];
    const int* idx = (const int*)d_in[1];
    float4* out = (float4*)d_out;

    const int total_threads = BATCH * 32;           // 3.2M
    const int block = 256;
    const int grid = (total_threads + block - 1) / block;  // 12500
    mean_agg_kernel<<<grid, block, 0, stream>>>(feat, idx, out);
}